// Round 1
// baseline (307.725 us; speedup 1.0000x reference)
//
#include <hip/hip_runtime.h>
#include <math.h>

#define NODES 1024
#define BATCH 16
#define TLEN 24
#define LAYERS 24
#define NLANES (NODES * BATCH) /* 16384 */
#define LOG2E 1.44269504088896340736f

#if __has_builtin(__builtin_amdgcn_rcpf)
__device__ __forceinline__ float fast_rcp(float x) { return __builtin_amdgcn_rcpf(x); }
#else
__device__ __forceinline__ float fast_rcp(float x) { return 1.0f / x; }
#endif

#if __has_builtin(__builtin_amdgcn_exp2f)
__device__ __forceinline__ float fast_exp2(float x) { return __builtin_amdgcn_exp2f(x); }
#else
__device__ __forceinline__ float fast_exp2(float x) { return exp2f(x); }
#endif

// One thread per (node, batch) lane. tid = node*16 + b (same ordering as the
// reference's flattened lane index node*B + b).
// Per pass p (horizon total): for each layer l, run T=24 GRU steps in-place on
// x[]; x[] becomes the next layer's input; h[l] carried across passes in LDS
// (dynamic layer index -> LDS, not scratch; t-loop fully unrolled -> x[] in regs).
__global__ __launch_bounds__(64) void gru_kernel(
    const float* __restrict__ inputs, const float* __restrict__ w_ih,
    const float* __restrict__ w_hh, const float* __restrict__ b_ih,
    const float* __restrict__ b_hh, const int* __restrict__ horizon_p,
    float* __restrict__ hv, float* __restrict__ inv_norm,
    float* __restrict__ h_out)
{
    __shared__ float Kc[LAYERS][10];
    __shared__ float hsh[LAYERS][64];
    const int ltid = threadIdx.x;
    const int tid = blockIdx.x * 64 + ltid;

    // Pre-scale per-layer params by -log2(e) so each sigmoid/tanh is a single
    // exp2 + rcp with fma-only argument build (shortens the h-dependent chain).
    if (ltid < LAYERS) {
        const int l = ltid;
        float wi0 = w_ih[l * 3 + 0], wi1 = w_ih[l * 3 + 1], wi2 = w_ih[l * 3 + 2];
        float wh0 = w_hh[l * 3 + 0], wh1 = w_hh[l * 3 + 1], wh2 = w_hh[l * 3 + 2];
        float bi0 = b_ih[l * 3 + 0], bi1 = b_ih[l * 3 + 1], bi2 = b_ih[l * 3 + 2];
        float bh0 = b_hh[l * 3 + 0], bh1 = b_hh[l * 3 + 1], bh2 = b_hh[l * 3 + 2];
        Kc[l][0] = -LOG2E * wi0;                 // rW
        Kc[l][1] = -LOG2E * wh0;                 // rU
        Kc[l][2] = -LOG2E * (bi0 + bh0);         // rC
        Kc[l][3] = -LOG2E * wi1;                 // zW
        Kc[l][4] = -LOG2E * wh1;                 // zU
        Kc[l][5] = -LOG2E * (bi1 + bh1);         // zC
        Kc[l][6] = -2.0f * LOG2E * wi2;          // nW (u2 = nW*x + nC)
        Kc[l][7] = -2.0f * LOG2E * bi2;          // nC
        Kc[l][8] = -2.0f * LOG2E * wh2;          // nU (v2 = nU*h + nD)
        Kc[l][9] = -2.0f * LOG2E * bh2;          // nD
    }
    #pragma unroll
    for (int l = 0; l < LAYERS; ++l) hsh[l][ltid] = 0.0f;
    __syncthreads();

    const int node = tid >> 4;
    const int b = tid & 15;
    // x[t, node*B + b] = inputs[b, 0, node, t]
    const float* xin = inputs + (size_t)b * (NODES * TLEN) + (size_t)node * TLEN;
    float x[TLEN];
    #pragma unroll
    for (int t4 = 0; t4 < TLEN / 4; ++t4) {
        float4 v = *reinterpret_cast<const float4*>(xin + t4 * 4);
        x[t4 * 4 + 0] = v.x; x[t4 * 4 + 1] = v.y;
        x[t4 * 4 + 2] = v.z; x[t4 * 4 + 3] = v.w;
    }

    const int H = *horizon_p;
    for (int p = 0; p < H; ++p) {
        for (int l = 0; l < LAYERS; ++l) {
            const float rW = Kc[l][0], rU = Kc[l][1], rC = Kc[l][2];
            const float zW = Kc[l][3], zU = Kc[l][4], zC = Kc[l][5];
            const float nW = Kc[l][6], nC = Kc[l][7];
            const float nU = Kc[l][8], nD = Kc[l][9];
            float h = hsh[l][ltid];
            #pragma unroll
            for (int t = 0; t < TLEN; ++t) {
                const float xt = x[t];
                // r = sigmoid(wi0*x+bi0 + wh0*h+bh0) = rcp(1 + 2^(rW*x+rC + rU*h))
                float er = fast_exp2(fmaf(rU, h, fmaf(rW, xt, rC)));
                float r  = fast_rcp(1.0f + er);
                float ez = fast_exp2(fmaf(zU, h, fmaf(zW, xt, zC)));
                float z  = fast_rcp(1.0f + ez);
                // n = tanh(a) = 2/(1+2^(-2a*log2e)) - 1, a = wi2*x+bi2 + r*(wh2*h+bh2)
                float u2 = fmaf(nW, xt, nC);
                float v2 = fmaf(nU, h, nD);
                float en = fast_exp2(fmaf(r, v2, u2));
                float n  = fmaf(2.0f, fast_rcp(1.0f + en), -1.0f);
                // h' = (1-z)*n + z*h = n + z*(h-n)
                h = fmaf(z, h - n, n);
                x[t] = h;
            }
            hsh[l][ltid] = h;
        }
    }

    // Epilogue: hv (scratch, [L][node*16+b]), h_out ([node][l][b]), inv_norm.
    for (int l = 0; l < LAYERS; ++l) {
        float h = hsh[l][ltid];
        hv[(size_t)l * NLANES + tid] = h;
        h_out[(size_t)node * (LAYERS * BATCH) + l * BATCH + b] = h;
        float s = h * h;
        s += __shfl_xor(s, 1);
        s += __shfl_xor(s, 2);
        s += __shfl_xor(s, 4);
        s += __shfl_xor(s, 8);
        if (b == 0)
            inv_norm[l * NODES + node] = fast_rcp(fmaxf(sqrtf(s), 1e-8f));
    }
}

// adj[l][i][j] = dot_b(hv[l,i,:], hv[l,j,:]) * inv[l,i] * inv[l,j]
// Block: one (layer, 64x64) tile; 256 threads; 4x4 outputs per thread.
__global__ __launch_bounds__(256) void adj_kernel(
    const float* __restrict__ hv, const float* __restrict__ inv_norm,
    float* __restrict__ adj)
{
    const int l = blockIdx.z;
    const int i0 = blockIdx.y * 64;
    const int j0 = blockIdx.x * 64;
    __shared__ float As[64 * 16];
    __shared__ float Bs[64 * 16];
    __shared__ float iA[64];
    __shared__ float iB[64];
    const int tid = threadIdx.x;
    const float* hvl = hv + (size_t)l * NLANES;

    ((float4*)As)[tid] = ((const float4*)(hvl + (size_t)i0 * 16))[tid];
    ((float4*)Bs)[tid] = ((const float4*)(hvl + (size_t)j0 * 16))[tid];
    if (tid < 64) iA[tid] = inv_norm[l * NODES + i0 + tid];
    else if (tid < 128) iB[tid - 64] = inv_norm[l * NODES + j0 + (tid - 64)];
    __syncthreads();

    const int ty = tid >> 4;  // 0..15 -> row group (4 rows)
    const int tx = tid & 15;  // 0..15 -> col group (4 cols)

    float4 a[4][4], bb[4][4];
    #pragma unroll
    for (int ii = 0; ii < 4; ++ii) {
        const int r = ty * 4 + ii;
        #pragma unroll
        for (int k = 0; k < 4; ++k) a[ii][k] = ((float4*)(As + r * 16))[k];
    }
    #pragma unroll
    for (int jj = 0; jj < 4; ++jj) {
        const int r = tx * 4 + jj;
        #pragma unroll
        for (int k = 0; k < 4; ++k) bb[jj][k] = ((float4*)(Bs + r * 16))[k];
    }

    float acc[4][4];
    #pragma unroll
    for (int ii = 0; ii < 4; ++ii)
        #pragma unroll
        for (int jj = 0; jj < 4; ++jj) {
            float s = 0.0f;
            #pragma unroll
            for (int k = 0; k < 4; ++k) {
                s = fmaf(a[ii][k].x, bb[jj][k].x, s);
                s = fmaf(a[ii][k].y, bb[jj][k].y, s);
                s = fmaf(a[ii][k].z, bb[jj][k].z, s);
                s = fmaf(a[ii][k].w, bb[jj][k].w, s);
            }
            acc[ii][jj] = s;
        }

    float* out = adj + (size_t)l * NODES * NODES;
    #pragma unroll
    for (int ii = 0; ii < 4; ++ii) {
        const int i = i0 + ty * 4 + ii;
        const float si = iA[ty * 4 + ii];
        float4 w;
        w.x = acc[ii][0] * si * iB[tx * 4 + 0];
        w.y = acc[ii][1] * si * iB[tx * 4 + 1];
        w.z = acc[ii][2] * si * iB[tx * 4 + 2];
        w.w = acc[ii][3] * si * iB[tx * 4 + 3];
        *(float4*)(out + (size_t)i * NODES + j0 + tx * 4) = w;
    }
}

extern "C" void kernel_launch(void* const* d_in, const int* in_sizes, int n_in,
                              void* d_out, int out_size, void* d_ws, size_t ws_size,
                              hipStream_t stream) {
    const float* inputs = (const float*)d_in[0];
    const float* w_ih   = (const float*)d_in[1];
    const float* w_hh   = (const float*)d_in[2];
    const float* b_ih   = (const float*)d_in[3];
    const float* b_hh   = (const float*)d_in[4];
    const int*   horiz  = (const int*)d_in[5];

    float* adj   = (float*)d_out;                                   // [24,1024,1024]
    float* h_out = (float*)d_out + (size_t)LAYERS * NODES * NODES;  // [1024,24,16]

    float* hv       = (float*)d_ws;                    // [24][16384]
    float* inv_norm = hv + (size_t)LAYERS * NLANES;    // [24][1024]

    gru_kernel<<<NLANES / 64, 64, 0, stream>>>(inputs, w_ih, w_hh, b_ih, b_hh,
                                               horiz, hv, inv_norm, h_out);

    dim3 grid(NODES / 64, NODES / 64, LAYERS);
    adj_kernel<<<grid, 256, 0, stream>>>(hv, inv_norm, adj);
}

// Round 2
// 105.962 us; speedup vs baseline: 2.9041x; 2.9041x over previous
//
#include <hip/hip_runtime.h>
#include <math.h>

#define NODES 1024
#define BATCH 16
#define TLEN 24
#define LAYERS 24
#define NLANES (NODES * BATCH) /* 16384 */
#define LOG2E 1.44269504088896340736f

#if __has_builtin(__builtin_amdgcn_rcpf)
__device__ __forceinline__ float fast_rcp(float x) { return __builtin_amdgcn_rcpf(x); }
#else
__device__ __forceinline__ float fast_rcp(float x) { return 1.0f / x; }
#endif

#if __has_builtin(__builtin_amdgcn_exp2f)
__device__ __forceinline__ float fast_exp2(float x) { return __builtin_amdgcn_exp2f(x); }
#else
__device__ __forceinline__ float fast_exp2(float x) { return exp2f(x); }
#endif

// Ring-pipelined GRU. Cell (pass p, layer l, time t) runs at tick p*24+l+t.
// Lane l (of a 24-lane ring, 2 rings per wave64: lanes 0-23 and 32-55) owns
// layer l's hidden state h forever (h carries across passes in-register).
// Every tick, lane l's input x is lane (l-1 mod 24)'s h from the previous
// tick (shuffle); lane 0 reads lane 23 (= previous pass's last-layer output)
// except during pass 0, where it reads the original input from LDS.
// Active window for lane l: ticks [l, l + H*24). 393216 threads -> 8 waves/SIMD.
__global__ __launch_bounds__(256) void gru_pipe_kernel(
    const float* __restrict__ inputs, const float* __restrict__ w_ih,
    const float* __restrict__ w_hh, const float* __restrict__ b_ih,
    const float* __restrict__ b_hh, const int* __restrict__ horizon_p,
    float* __restrict__ hv, float* __restrict__ h_out)
{
    __shared__ float xl[8][TLEN];  // original input seq per chain
    const int tid = threadIdx.x;
    const int wid = tid >> 6;
    const int lane = tid & 63;
    const int half = lane >> 5;
    const int l = lane & 31;              // layer index if < 24
    const bool is_layer = (l < LAYERS);
    const int ll = is_layer ? l : 0;
    const int chain_local = wid * 2 + half;            // 0..7
    const int chain = blockIdx.x * 8 + chain_local;    // 0..16383
    const int node = chain >> 4;
    const int b = chain & 15;

    // Per-lane (per-layer) GRU constants, pre-scaled by -log2(e) so each
    // gate is exp2 + (shared) rcp. Gate order in weights: r, z, n.
    const float wi0 = w_ih[ll * 3 + 0], wi1 = w_ih[ll * 3 + 1], wi2 = w_ih[ll * 3 + 2];
    const float wh0 = w_hh[ll * 3 + 0], wh1 = w_hh[ll * 3 + 1], wh2 = w_hh[ll * 3 + 2];
    const float bi0 = b_ih[ll * 3 + 0], bi1 = b_ih[ll * 3 + 1], bi2 = b_ih[ll * 3 + 2];
    const float bh0 = b_hh[ll * 3 + 0], bh1 = b_hh[ll * 3 + 1], bh2 = b_hh[ll * 3 + 2];
    const float rW = -LOG2E * wi0, rU = -LOG2E * wh0, rC = -LOG2E * (bi0 + bh0);
    const float zW = -LOG2E * wi1, zU = -LOG2E * wh1, zC = -LOG2E * (bi1 + bh1);
    const float nW = -2.0f * LOG2E * wi2, nC = -2.0f * LOG2E * bi2;
    const float nU = -2.0f * LOG2E * wh2, nD = -2.0f * LOG2E * bh2;

    // Stage this chain's input sequence: x[t] = inputs[b,0,node,t]
    if (is_layer)
        xl[chain_local][l] = inputs[((size_t)b * NODES + node) * TLEN + l];
    __syncthreads();

    const int H = *horizon_p;
    const int nticks = H * TLEN + LAYERS - 1;          // 215 for H=8
    const int kstart = l;
    const int kend = l + H * TLEN;
    const int ringsrc = (half << 5) | (is_layer ? ((l == 0) ? (LAYERS - 1) : (l - 1)) : l);
    const bool lane0 = (l == 0);
    const float* xrow = &xl[chain_local][0];

    float h = 0.0f;
    for (int k = 0; k < nticks; ++k) {
        float xin = __shfl(h, ringsrc, 64);            // ring handoff (prev tick's h)
        if (k < TLEN) {                                // wave-uniform branch (fill phase)
            float xf = xrow[k];                        // broadcast LDS read
            if (lane0) xin = xf;
        }
        const bool act = is_layer && (k >= kstart) && (k < kend);
        // r = sigmoid(ar), er = 2^(-ar*log2e)
        float er = fast_exp2(fmaf(rU, h, fmaf(rW, xin, rC)));
        float r  = fast_rcp(1.0f + er);
        float ez = fast_exp2(fmaf(zU, h, fmaf(zW, xin, zC)));
        // en = 2^(-2*an*log2e);  n = (1-en)/(1+en);  z = 1/(1+ez)
        float en = fast_exp2(fmaf(r, fmaf(nU, h, nD), fmaf(nW, xin, nC)));
        // h' = (1-z)n + z h = (ez(1-en) + h(1+en)) / ((1+ez)(1+en))  -- one rcp
        float num = fmaf(en, h - ez, h + ez);
        float den = (1.0f + ez) * (1.0f + en);
        float hn = num * fast_rcp(den);
        h = act ? hn : h;
    }

    if (is_layer) {
        hv[(size_t)l * NLANES + chain] = h;                              // [L][chain]
        h_out[(size_t)node * (LAYERS * BATCH) + l * BATCH + b] = h;      // [node][l][b]
    }
}

// adj[l][i][j] = dot_b(hv[l,i,:], hv[l,j,:]) * inv_i * inv_j.
// 64x64 tile per 256-thread block. B tile stored TRANSPOSED in LDS so the
// per-thread B reads are 64-consecutive-float b128s (conflict-free); A reads
// are same-address broadcasts. Norms computed in-block (no inv_norm scratch).
__global__ __launch_bounds__(256) void adj_kernel(
    const float* __restrict__ hv, float* __restrict__ adj)
{
    const int l = blockIdx.z;
    const int i0 = blockIdx.y * 64;
    const int j0 = blockIdx.x * 64;
    __shared__ float As[64 * 16];   // [row][k]
    __shared__ float Bt[16 * 64];   // [k][col]
    __shared__ float iA[64];
    __shared__ float iB[64];
    const int tid = threadIdx.x;
    const float* hvl = hv + (size_t)l * NLANES;

    ((float4*)As)[tid] = ((const float4*)(hvl + (size_t)i0 * 16))[tid];
    {
        const int j = tid >> 2;
        const int kc = (tid & 3) * 4;
        float4 bv = *(const float4*)(hvl + (size_t)(j0 + j) * 16 + kc);
        Bt[(kc + 0) * 64 + j] = bv.x;
        Bt[(kc + 1) * 64 + j] = bv.y;
        Bt[(kc + 2) * 64 + j] = bv.z;
        Bt[(kc + 3) * 64 + j] = bv.w;
    }
    __syncthreads();

    if (tid < 64) {
        float s = 0.0f;
        #pragma unroll
        for (int k = 0; k < 16; ++k) { float v = As[tid * 16 + k]; s = fmaf(v, v, s); }
        iA[tid] = fast_rcp(fmaxf(sqrtf(s), 1e-8f));
    } else if (tid < 128) {
        const int j = tid - 64;
        float s = 0.0f;
        #pragma unroll
        for (int k = 0; k < 16; ++k) { float v = Bt[k * 64 + j]; s = fmaf(v, v, s); }
        iB[j] = fast_rcp(fmaxf(sqrtf(s), 1e-8f));
    }
    __syncthreads();

    const int ty = tid >> 4;   // row group (4 rows)
    const int tx = tid & 15;   // col group (4 cols = 1 float4)

    float4 acc0 = {0,0,0,0}, acc1 = {0,0,0,0}, acc2 = {0,0,0,0}, acc3 = {0,0,0,0};
    #pragma unroll
    for (int kk = 0; kk < 4; ++kk) {
        // A fragments: rows ty*4+ii, k-chunk kk (broadcast b128 reads)
        float4 a0 = ((const float4*)As)[(ty * 4 + 0) * 4 + kk];
        float4 a1 = ((const float4*)As)[(ty * 4 + 1) * 4 + kk];
        float4 a2 = ((const float4*)As)[(ty * 4 + 2) * 4 + kk];
        float4 a3 = ((const float4*)As)[(ty * 4 + 3) * 4 + kk];
        #pragma unroll
        for (int e = 0; e < 4; ++e) {
            const int k = kk * 4 + e;
            float4 bk = ((const float4*)Bt)[k * 16 + tx];  // 4 cols at k
            const float a0e = (e == 0) ? a0.x : (e == 1) ? a0.y : (e == 2) ? a0.z : a0.w;
            const float a1e = (e == 0) ? a1.x : (e == 1) ? a1.y : (e == 2) ? a1.z : a1.w;
            const float a2e = (e == 0) ? a2.x : (e == 1) ? a2.y : (e == 2) ? a2.z : a2.w;
            const float a3e = (e == 0) ? a3.x : (e == 1) ? a3.y : (e == 2) ? a3.z : a3.w;
            acc0.x = fmaf(a0e, bk.x, acc0.x); acc0.y = fmaf(a0e, bk.y, acc0.y);
            acc0.z = fmaf(a0e, bk.z, acc0.z); acc0.w = fmaf(a0e, bk.w, acc0.w);
            acc1.x = fmaf(a1e, bk.x, acc1.x); acc1.y = fmaf(a1e, bk.y, acc1.y);
            acc1.z = fmaf(a1e, bk.z, acc1.z); acc1.w = fmaf(a1e, bk.w, acc1.w);
            acc2.x = fmaf(a2e, bk.x, acc2.x); acc2.y = fmaf(a2e, bk.y, acc2.y);
            acc2.z = fmaf(a2e, bk.z, acc2.z); acc2.w = fmaf(a2e, bk.w, acc2.w);
            acc3.x = fmaf(a3e, bk.x, acc3.x); acc3.y = fmaf(a3e, bk.y, acc3.y);
            acc3.z = fmaf(a3e, bk.z, acc3.z); acc3.w = fmaf(a3e, bk.w, acc3.w);
        }
    }

    float* out = adj + (size_t)l * NODES * NODES;
    const float4 ib4 = ((const float4*)iB)[tx];
    #pragma unroll
    for (int ii = 0; ii < 4; ++ii) {
        const int i = i0 + ty * 4 + ii;
        const float si = iA[ty * 4 + ii];
        float4 a = (ii == 0) ? acc0 : (ii == 1) ? acc1 : (ii == 2) ? acc2 : acc3;
        float4 w;
        w.x = a.x * si * ib4.x;
        w.y = a.y * si * ib4.y;
        w.z = a.z * si * ib4.z;
        w.w = a.w * si * ib4.w;
        *(float4*)(out + (size_t)i * NODES + j0 + tx * 4) = w;
    }
}

extern "C" void kernel_launch(void* const* d_in, const int* in_sizes, int n_in,
                              void* d_out, int out_size, void* d_ws, size_t ws_size,
                              hipStream_t stream) {
    const float* inputs = (const float*)d_in[0];
    const float* w_ih   = (const float*)d_in[1];
    const float* w_hh   = (const float*)d_in[2];
    const float* b_ih   = (const float*)d_in[3];
    const float* b_hh   = (const float*)d_in[4];
    const int*   horiz  = (const int*)d_in[5];

    float* adj   = (float*)d_out;                                   // [24,1024,1024]
    float* h_out = (float*)d_out + (size_t)LAYERS * NODES * NODES;  // [1024,24,16]
    float* hv    = (float*)d_ws;                                    // [24][16384]

    // 2048 blocks x 256 threads = 8192 waves (8 chains/block, 2 per wave)
    gru_pipe_kernel<<<NLANES / 8, 256, 0, stream>>>(inputs, w_ih, w_hh, b_ih, b_hh,
                                                    horiz, hv, h_out);

    dim3 grid(NODES / 64, NODES / 64, LAYERS);
    adj_kernel<<<grid, 256, 0, stream>>>(hv, adj);
}

// Round 4
// 99.301 us; speedup vs baseline: 3.0989x; 1.0671x over previous
//
#include <hip/hip_runtime.h>
#include <math.h>

#define NODES 1024
#define BATCH 16
#define TLEN 24
#define LAYERS 24
#define NLANES (NODES * BATCH) /* 16384 */
#define LOG2E 1.44269504088896340736f

typedef float v2f __attribute__((ext_vector_type(2)));

#if __has_builtin(__builtin_amdgcn_rcpf)
__device__ __forceinline__ float fast_rcp(float x) { return __builtin_amdgcn_rcpf(x); }
#else
__device__ __forceinline__ float fast_rcp(float x) { return 1.0f / x; }
#endif

#if __has_builtin(__builtin_amdgcn_exp2f)
__device__ __forceinline__ float fast_exp2(float x) { return __builtin_amdgcn_exp2f(x); }
#else
__device__ __forceinline__ float fast_exp2(float x) { return exp2f(x); }
#endif

// Packed math via COMPILER vector ops (no inline asm). AMDGPU ISel lowers
// <2 x float> fma/add/mul to v_pk_fma_f32/v_pk_add_f32/v_pk_mul_f32 on
// gfx90a+ (packed-FP32); if it scalarizes, semantics are identical.
#if __has_builtin(__builtin_elementwise_fma)
__device__ __forceinline__ v2f pk_fma(v2f a, v2f b, v2f c) {
    return __builtin_elementwise_fma(a, b, c);
}
#else
__device__ __forceinline__ v2f pk_fma(v2f a, v2f b, v2f c) {
    v2f d; d.x = fmaf(a.x, b.x, c.x); d.y = fmaf(a.y, b.y, c.y); return d;
}
#endif
__device__ __forceinline__ v2f pk_add(v2f a, v2f b) { return a + b; }
__device__ __forceinline__ v2f pk_mul(v2f a, v2f b) { return a * b; }

struct GruK {
    v2f rW, rU, rC, zW, zU, zC, nW, nC, nU, nD;
};

// One GRU cell for 2 packed chains. ~15 pk-VALU + 10 transcendental.
// er/ez/en are e^{-a} forms (weights pre-scaled by -log2e):
// r = 1/(1+er); n = (1-en)/(1+en); z = 1/(1+ez);
// h' = (1-z)n + zh = (ez*(1-en) + h*(1+en)) / ((1+ez)*(1+en))  -- one rcp.
__device__ __forceinline__ v2f gru_cell(const GruK& K, v2f h, v2f xin) {
    const v2f ONE = (v2f){1.0f, 1.0f};
    v2f ar = pk_fma(K.rU, h, pk_fma(K.rW, xin, K.rC));
    v2f az = pk_fma(K.zU, h, pk_fma(K.zW, xin, K.zC));
    v2f er; er.x = fast_exp2(ar.x); er.y = fast_exp2(ar.y);
    v2f ez; ez.x = fast_exp2(az.x); ez.y = fast_exp2(az.y);
    v2f er1 = pk_add(er, ONE);
    v2f r;  r.x = fast_rcp(er1.x); r.y = fast_rcp(er1.y);
    v2f an = pk_fma(r, pk_fma(K.nU, h, K.nD), pk_fma(K.nW, xin, K.nC));
    v2f en; en.x = fast_exp2(an.x); en.y = fast_exp2(an.y);
    v2f num = pk_fma(en, h - ez, h + ez);    // en*(h-ez) + (h+ez)
    v2f den = pk_mul(pk_add(ez, ONE), pk_add(en, ONE));
    v2f rd; rd.x = fast_rcp(den.x); rd.y = fast_rcp(den.y);
    return pk_mul(num, rd);
}

// Ring-pipelined GRU, 2 chains packed per lane, round-2 masked single loop.
// Cell (pass p, layer l, time t) runs at tick p*24 + l + t. Lane l of a
// 24-lane ring owns layer l; wave64 = 2 rings (lanes 0-23, 32-55); each lane
// carries TWO chains in a v2f. Lane l active for ticks [l, l + H*24).
__global__ __launch_bounds__(256) void gru_pipe_kernel(
    const float* __restrict__ inputs, const float* __restrict__ w_ih,
    const float* __restrict__ w_hh, const float* __restrict__ b_ih,
    const float* __restrict__ b_hh, const int* __restrict__ horizon_p,
    float* __restrict__ hv, float* __restrict__ h_out)
{
    __shared__ float xl[16][TLEN];   // 16 chains per block
    const int tid = threadIdx.x;
    const int wid = tid >> 6;
    const int lane = tid & 63;
    const int hw = lane >> 5;
    const int l = lane & 31;                 // layer if < 24
    const bool is_layer = (l < LAYERS);
    const int ll = is_layer ? l : 0;
    const int pair_local = wid * 2 + hw;     // 0..7
    const int c0 = blockIdx.x * 16 + pair_local * 2;  // first of 2 chains

    // Per-layer constants, duplicated into both packed halves.
    GruK K;
    {
        const float wi0 = w_ih[ll*3+0], wi1 = w_ih[ll*3+1], wi2 = w_ih[ll*3+2];
        const float wh0 = w_hh[ll*3+0], wh1 = w_hh[ll*3+1], wh2 = w_hh[ll*3+2];
        const float bi0 = b_ih[ll*3+0], bi1 = b_ih[ll*3+1], bi2 = b_ih[ll*3+2];
        const float bh0 = b_hh[ll*3+0], bh1 = b_hh[ll*3+1], bh2 = b_hh[ll*3+2];
        float rW = -LOG2E * wi0, rU = -LOG2E * wh0, rC = -LOG2E * (bi0 + bh0);
        float zW = -LOG2E * wi1, zU = -LOG2E * wh1, zC = -LOG2E * (bi1 + bh1);
        float nW = -2.0f*LOG2E * wi2, nC = -2.0f*LOG2E * bi2;
        float nU = -2.0f*LOG2E * wh2, nD = -2.0f*LOG2E * bh2;
        K.rW = (v2f){rW, rW}; K.rU = (v2f){rU, rU}; K.rC = (v2f){rC, rC};
        K.zW = (v2f){zW, zW}; K.zU = (v2f){zU, zU}; K.zC = (v2f){zC, zC};
        K.nW = (v2f){nW, nW}; K.nC = (v2f){nC, nC};
        K.nU = (v2f){nU, nU}; K.nD = (v2f){nD, nD};
    }

    // Stage both chains' input sequences (round-2 style: layer-lane l writes t=l).
    // chain c: node = c>>4, b = c&15; x[t] = inputs[b,0,node,t].
    if (is_layer) {
        const int node0 = c0 >> 4, b0 = c0 & 15;       // c0 even -> c0+1 same node
        xl[pair_local * 2][l]     = inputs[((size_t)b0 * NODES + node0) * TLEN + l];
        xl[pair_local * 2 + 1][l] = inputs[((size_t)(b0 + 1) * NODES + node0) * TLEN + l];
    }
    __syncthreads();

    const int H = *horizon_p;
    const int nticks = H * TLEN + LAYERS - 1;          // 215 for H=8
    const int kstart = l;
    const int kend = l + H * TLEN;
    const int ringsrc = (hw << 5) | (is_layer ? ((l == 0) ? (LAYERS - 1) : (l - 1)) : l);
    const bool lane0 = is_layer && (l == 0);
    const float* x0 = &xl[pair_local * 2][0];
    const float* x1 = &xl[pair_local * 2 + 1][0];

    v2f h = (v2f){0.0f, 0.0f};
    for (int k = 0; k < nticks; ++k) {
        v2f xin;
        xin.x = __shfl(h.x, ringsrc, 64);
        xin.y = __shfl(h.y, ringsrc, 64);
        if (k < TLEN) {                                // wave-uniform (fill phase)
            float xf0 = x0[k], xf1 = x1[k];
            if (lane0) { xin.x = xf0; xin.y = xf1; }
        }
        const bool act = is_layer && (k >= kstart) && (k < kend);
        v2f hn = gru_cell(K, h, xin);
        h.x = act ? hn.x : h.x;
        h.y = act ? hn.y : h.y;
    }

    if (is_layer) {
        *(v2f*)(hv + (size_t)l * NLANES + c0) = h;     // hv[l][c0], c0+1 adjacent
        const int node = c0 >> 4, b = c0 & 15;
        float* ho = h_out + (size_t)node * (LAYERS * BATCH) + l * BATCH + b;
        ho[0] = h.x;
        ho[1] = h.y;
    }
}

// adj[l][i][j] = dot_b(hv[l,i,:], hv[l,j,:]) * inv_i * inv_j.
// 64x64 tile per 256-thread block. B tile stored TRANSPOSED in LDS so the
// per-thread B reads are 64-consecutive-float b128s (conflict-free); A reads
// are same-address broadcasts. Norms computed in-block.
__global__ __launch_bounds__(256) void adj_kernel(
    const float* __restrict__ hv, float* __restrict__ adj)
{
    const int l = blockIdx.z;
    const int i0 = blockIdx.y * 64;
    const int j0 = blockIdx.x * 64;
    __shared__ float As[64 * 16];   // [row][k]
    __shared__ float Bt[16 * 64];   // [k][col]
    __shared__ float iA[64];
    __shared__ float iB[64];
    const int tid = threadIdx.x;
    const float* hvl = hv + (size_t)l * NLANES;

    ((float4*)As)[tid] = ((const float4*)(hvl + (size_t)i0 * 16))[tid];
    {
        const int j = tid >> 2;
        const int kc = (tid & 3) * 4;
        float4 bv = *(const float4*)(hvl + (size_t)(j0 + j) * 16 + kc);
        Bt[(kc + 0) * 64 + j] = bv.x;
        Bt[(kc + 1) * 64 + j] = bv.y;
        Bt[(kc + 2) * 64 + j] = bv.z;
        Bt[(kc + 3) * 64 + j] = bv.w;
    }
    __syncthreads();

    if (tid < 64) {
        float s = 0.0f;
        #pragma unroll
        for (int k = 0; k < 16; ++k) { float v = As[tid * 16 + k]; s = fmaf(v, v, s); }
        iA[tid] = fast_rcp(fmaxf(sqrtf(s), 1e-8f));
    } else if (tid < 128) {
        const int j = tid - 64;
        float s = 0.0f;
        #pragma unroll
        for (int k = 0; k < 16; ++k) { float v = Bt[k * 64 + j]; s = fmaf(v, v, s); }
        iB[j] = fast_rcp(fmaxf(sqrtf(s), 1e-8f));
    }
    __syncthreads();

    const int ty = tid >> 4;   // row group (4 rows)
    const int tx = tid & 15;   // col group (4 cols = 1 float4)

    float4 acc0 = {0,0,0,0}, acc1 = {0,0,0,0}, acc2 = {0,0,0,0}, acc3 = {0,0,0,0};
    #pragma unroll
    for (int kk = 0; kk < 4; ++kk) {
        float4 a0 = ((const float4*)As)[(ty * 4 + 0) * 4 + kk];
        float4 a1 = ((const float4*)As)[(ty * 4 + 1) * 4 + kk];
        float4 a2 = ((const float4*)As)[(ty * 4 + 2) * 4 + kk];
        float4 a3 = ((const float4*)As)[(ty * 4 + 3) * 4 + kk];
        #pragma unroll
        for (int e = 0; e < 4; ++e) {
            const int k = kk * 4 + e;
            float4 bk = ((const float4*)Bt)[k * 16 + tx];
            const float a0e = (e == 0) ? a0.x : (e == 1) ? a0.y : (e == 2) ? a0.z : a0.w;
            const float a1e = (e == 0) ? a1.x : (e == 1) ? a1.y : (e == 2) ? a1.z : a1.w;
            const float a2e = (e == 0) ? a2.x : (e == 1) ? a2.y : (e == 2) ? a2.z : a2.w;
            const float a3e = (e == 0) ? a3.x : (e == 1) ? a3.y : (e == 2) ? a3.z : a3.w;
            acc0.x = fmaf(a0e, bk.x, acc0.x); acc0.y = fmaf(a0e, bk.y, acc0.y);
            acc0.z = fmaf(a0e, bk.z, acc0.z); acc0.w = fmaf(a0e, bk.w, acc0.w);
            acc1.x = fmaf(a1e, bk.x, acc1.x); acc1.y = fmaf(a1e, bk.y, acc1.y);
            acc1.z = fmaf(a1e, bk.z, acc1.z); acc1.w = fmaf(a1e, bk.w, acc1.w);
            acc2.x = fmaf(a2e, bk.x, acc2.x); acc2.y = fmaf(a2e, bk.y, acc2.y);
            acc2.z = fmaf(a2e, bk.z, acc2.z); acc2.w = fmaf(a2e, bk.w, acc2.w);
            acc3.x = fmaf(a3e, bk.x, acc3.x); acc3.y = fmaf(a3e, bk.y, acc3.y);
            acc3.z = fmaf(a3e, bk.z, acc3.z); acc3.w = fmaf(a3e, bk.w, acc3.w);
        }
    }

    float* out = adj + (size_t)l * NODES * NODES;
    const float4 ib4 = ((const float4*)iB)[tx];
    #pragma unroll
    for (int ii = 0; ii < 4; ++ii) {
        const int i = i0 + ty * 4 + ii;
        const float si = iA[ty * 4 + ii];
        float4 a = (ii == 0) ? acc0 : (ii == 1) ? acc1 : (ii == 2) ? acc2 : acc3;
        float4 w;
        w.x = a.x * si * ib4.x;
        w.y = a.y * si * ib4.y;
        w.z = a.z * si * ib4.z;
        w.w = a.w * si * ib4.w;
        *(float4*)(out + (size_t)i * NODES + j0 + tx * 4) = w;
    }
}

extern "C" void kernel_launch(void* const* d_in, const int* in_sizes, int n_in,
                              void* d_out, int out_size, void* d_ws, size_t ws_size,
                              hipStream_t stream) {
    const float* inputs = (const float*)d_in[0];
    const float* w_ih   = (const float*)d_in[1];
    const float* w_hh   = (const float*)d_in[2];
    const float* b_ih   = (const float*)d_in[3];
    const float* b_hh   = (const float*)d_in[4];
    const int*   horiz  = (const int*)d_in[5];

    float* adj   = (float*)d_out;                                   // [24,1024,1024]
    float* h_out = (float*)d_out + (size_t)LAYERS * NODES * NODES;  // [1024,24,16]
    float* hv    = (float*)d_ws;                                    // [24][16384]

    // 1024 blocks x 256 threads = 4096 waves; 16 chains/block (2 per lane)
    gru_pipe_kernel<<<NLANES / 16, 256, 0, stream>>>(inputs, w_ih, w_hh, b_ih, b_hh,
                                                     horiz, hv, h_out);

    dim3 grid(NODES / 64, NODES / 64, LAYERS);
    adj_kernel<<<grid, 256, 0, stream>>>(hv, adj);
}

// Round 5
// 82.457 us; speedup vs baseline: 3.7319x; 1.2043x over previous
//
#include <hip/hip_runtime.h>
#include <math.h>

#define NODES 1024
#define BATCH 16
#define TLEN 24
#define LAYERS 24
#define NLANES (NODES * BATCH) /* 16384 */
#define LOG2E 1.44269504088896340736f

typedef float v2f __attribute__((ext_vector_type(2)));

#if __has_builtin(__builtin_amdgcn_rcpf)
__device__ __forceinline__ float fast_rcp(float x) { return __builtin_amdgcn_rcpf(x); }
#else
__device__ __forceinline__ float fast_rcp(float x) { return 1.0f / x; }
#endif

#if __has_builtin(__builtin_amdgcn_exp2f)
__device__ __forceinline__ float fast_exp2(float x) { return __builtin_amdgcn_exp2f(x); }
#else
__device__ __forceinline__ float fast_exp2(float x) { return exp2f(x); }
#endif

// Packed math via COMPILER vector ops (no inline asm) -> v_pk_* on gfx950.
#if __has_builtin(__builtin_elementwise_fma)
__device__ __forceinline__ v2f pk_fma(v2f a, v2f b, v2f c) {
    return __builtin_elementwise_fma(a, b, c);
}
#else
__device__ __forceinline__ v2f pk_fma(v2f a, v2f b, v2f c) {
    v2f d; d.x = fmaf(a.x, b.x, c.x); d.y = fmaf(a.y, b.y, c.y); return d;
}
#endif

struct GruK {
    v2f rW, rU, rC, zW, zU, zC, nW, nC, nU, nD;
};

__device__ __forceinline__ GruK make_k(
    const float* __restrict__ w_ih, const float* __restrict__ w_hh,
    const float* __restrict__ b_ih, const float* __restrict__ b_hh, int l)
{
    GruK K;
    const float wi0 = w_ih[l*3+0], wi1 = w_ih[l*3+1], wi2 = w_ih[l*3+2];
    const float wh0 = w_hh[l*3+0], wh1 = w_hh[l*3+1], wh2 = w_hh[l*3+2];
    const float bi0 = b_ih[l*3+0], bi1 = b_ih[l*3+1], bi2 = b_ih[l*3+2];
    const float bh0 = b_hh[l*3+0], bh1 = b_hh[l*3+1], bh2 = b_hh[l*3+2];
    float rW = -LOG2E * wi0, rU = -LOG2E * wh0, rC = -LOG2E * (bi0 + bh0);
    float zW = -LOG2E * wi1, zU = -LOG2E * wh1, zC = -LOG2E * (bi1 + bh1);
    float nW = -2.0f*LOG2E * wi2, nC = -2.0f*LOG2E * bi2;
    float nU = -2.0f*LOG2E * wh2, nD = -2.0f*LOG2E * bh2;
    K.rW = (v2f){rW, rW}; K.rU = (v2f){rU, rU}; K.rC = (v2f){rC, rC};
    K.zW = (v2f){zW, zW}; K.zU = (v2f){zU, zU}; K.zC = (v2f){zC, zC};
    K.nW = (v2f){nW, nW}; K.nC = (v2f){nC, nC};
    K.nU = (v2f){nU, nU}; K.nD = (v2f){nD, nD};
    return K;
}

// One GRU cell for 2 packed chains (bit-identical to the passing round-4 form).
// er/ez/en are e^{-a} forms (weights pre-scaled by -log2e):
// r = 1/(1+er); h' = (ez*(1-en) + h*(1+en)) / ((1+ez)*(1+en))  -- one final rcp.
__device__ __forceinline__ v2f gru_cell(const GruK& K, v2f h, v2f xin) {
    const v2f ONE = (v2f){1.0f, 1.0f};
    v2f ar = pk_fma(K.rU, h, pk_fma(K.rW, xin, K.rC));
    v2f az = pk_fma(K.zU, h, pk_fma(K.zW, xin, K.zC));
    v2f er; er.x = fast_exp2(ar.x); er.y = fast_exp2(ar.y);
    v2f ez; ez.x = fast_exp2(az.x); ez.y = fast_exp2(az.y);
    v2f er1 = er + ONE;
    v2f r;  r.x = fast_rcp(er1.x); r.y = fast_rcp(er1.y);
    v2f an = pk_fma(r, pk_fma(K.nU, h, K.nD), pk_fma(K.nW, xin, K.nC));
    v2f en; en.x = fast_exp2(an.x); en.y = fast_exp2(an.y);
    v2f num = pk_fma(en, h - ez, h + ez);
    v2f den = (ez + ONE) * (en + ONE);
    v2f rd; rd.x = fast_rcp(den.x); rd.y = fast_rcp(den.y);
    return num * rd;
}

// Ring-pipelined GRU: 8-lane rings, 3 layers per lane, 2 chains packed/lane.
// Lane i (ring-local) owns layers {3i, 3i+1, 3i+2}. Cell (p,l,t) at tick
// p*24+l+t. Slot-1/2 inputs are the lane's own slot-0/1 h from the previous
// tick (registers); slot-0 input is prev lane's slot-2 h (one shfl), and the
// pass wrap (layer 0 <- layer 23, prev tick) is the SAME shfl on ring lane 0.
// Wave64 = 8 rings, all lanes active: 16 chains/wave, 384 cells/wave-tick.
__global__ __launch_bounds__(256) void gru_pipe_kernel(
    const float* __restrict__ inputs, const float* __restrict__ w_ih,
    const float* __restrict__ w_hh, const float* __restrict__ b_ih,
    const float* __restrict__ b_hh, const int* __restrict__ horizon_p,
    float* __restrict__ hv, float* __restrict__ h_out)
{
    __shared__ float xl[64][TLEN];   // 64 chains per block
    const int tid = threadIdx.x;
    const int wid = tid >> 6;
    const int lane = tid & 63;
    const int sl = lane & 7;          // ring-local lane
    const int L0 = sl * 3;            // owns layers L0, L0+1, L0+2
    const int ring = lane >> 3;       // 0..7 within wave
    const int c_local = wid * 16 + ring * 2;          // even, 0..62
    const int c0 = blockIdx.x * 64 + c_local;         // chains c0, c0+1

    const GruK K0 = make_k(w_ih, w_hh, b_ih, b_hh, L0);
    const GruK K1 = make_k(w_ih, w_hh, b_ih, b_hh, L0 + 1);
    const GruK K2 = make_k(w_ih, w_hh, b_ih, b_hh, L0 + 2);

    // Stage the block's 64 chains' input sequences: xl[c][t] = inputs[b,0,node,t]
    for (int i = tid; i < 64 * TLEN; i += 256) {
        const int cl = i / TLEN, t = i % TLEN;
        const int c = blockIdx.x * 64 + cl;
        const int node = c >> 4, b = c & 15;
        xl[cl][t] = inputs[((size_t)b * NODES + node) * TLEN + t];
    }
    __syncthreads();

    const int H = *horizon_p;
    const int last = H * TLEN;                         // 192 for H=8
    const int ringsrc = (lane & 56) | ((sl + 7) & 7);  // prev lane in 8-ring
    const bool lead = (sl == 0);
    const float* x0 = &xl[c_local][0];
    const float* x1 = &xl[c_local + 1][0];

    v2f h0 = (v2f){0.0f, 0.0f}, h1 = h0, h2 = h0;

    // Fill: ticks [0, 24). Ring lane 0 slot 0 takes the original input.
    for (int k = 0; k < TLEN; ++k) {
        v2f xin;
        xin.x = __shfl(h2.x, ringsrc, 64);
        xin.y = __shfl(h2.y, ringsrc, 64);
        if (lead) { xin.x = x0[k]; xin.y = x1[k]; }
        v2f n0 = gru_cell(K0, h0, xin);
        v2f n1 = gru_cell(K1, h1, h0);
        v2f n2 = gru_cell(K2, h2, h1);
        h0 = (k >= L0)     ? n0 : h0;
        h1 = (k >= L0 + 1) ? n1 : h1;
        h2 = (k >= L0 + 2) ? n2 : h2;
    }
    // Steady: ticks [24, last) — all slots active, no masks.
    for (int k = TLEN; k < last; ++k) {
        v2f xin;
        xin.x = __shfl(h2.x, ringsrc, 64);
        xin.y = __shfl(h2.y, ringsrc, 64);
        v2f p0 = h0, p1 = h1;
        h0 = gru_cell(K0, h0, xin);
        h1 = gru_cell(K1, h1, p0);
        h2 = gru_cell(K2, h2, p1);
    }
    // Drain: ticks [last, last+23). Slot s finishes at k = L0+s+last.
    for (int k = last; k < last + LAYERS - 1; ++k) {
        v2f xin;
        xin.x = __shfl(h2.x, ringsrc, 64);
        xin.y = __shfl(h2.y, ringsrc, 64);
        v2f n0 = gru_cell(K0, h0, xin);
        v2f n1 = gru_cell(K1, h1, h0);
        v2f n2 = gru_cell(K2, h2, h1);
        h0 = (k < L0 + last)     ? n0 : h0;
        h1 = (k < L0 + 1 + last) ? n1 : h1;
        h2 = (k < L0 + 2 + last) ? n2 : h2;
    }

    // Outputs: hv[L][c0..c0+1] (v2f) and h_out[node][L][b..b+1] (v2f, b even).
    *(v2f*)(hv + (size_t)(L0 + 0) * NLANES + c0) = h0;
    *(v2f*)(hv + (size_t)(L0 + 1) * NLANES + c0) = h1;
    *(v2f*)(hv + (size_t)(L0 + 2) * NLANES + c0) = h2;
    const int node = c0 >> 4, b = c0 & 15;
    float* ho = h_out + (size_t)node * (LAYERS * BATCH) + b;
    *(v2f*)(ho + (L0 + 0) * BATCH) = h0;
    *(v2f*)(ho + (L0 + 1) * BATCH) = h1;
    *(v2f*)(ho + (L0 + 2) * BATCH) = h2;
}

// adj[l][i][j] = dot_b(hv[l,i,:], hv[l,j,:]) * inv_i * inv_j.
// 64x64 tile per 256-thread block; B tile transposed in LDS (conflict-free).
__global__ __launch_bounds__(256) void adj_kernel(
    const float* __restrict__ hv, float* __restrict__ adj)
{
    const int l = blockIdx.z;
    const int i0 = blockIdx.y * 64;
    const int j0 = blockIdx.x * 64;
    __shared__ float As[64 * 16];   // [row][k]
    __shared__ float Bt[16 * 64];   // [k][col]
    __shared__ float iA[64];
    __shared__ float iB[64];
    const int tid = threadIdx.x;
    const float* hvl = hv + (size_t)l * NLANES;

    ((float4*)As)[tid] = ((const float4*)(hvl + (size_t)i0 * 16))[tid];
    {
        const int j = tid >> 2;
        const int kc = (tid & 3) * 4;
        float4 bv = *(const float4*)(hvl + (size_t)(j0 + j) * 16 + kc);
        Bt[(kc + 0) * 64 + j] = bv.x;
        Bt[(kc + 1) * 64 + j] = bv.y;
        Bt[(kc + 2) * 64 + j] = bv.z;
        Bt[(kc + 3) * 64 + j] = bv.w;
    }
    __syncthreads();

    if (tid < 64) {
        float s = 0.0f;
        #pragma unroll
        for (int k = 0; k < 16; ++k) { float v = As[tid * 16 + k]; s = fmaf(v, v, s); }
        iA[tid] = fast_rcp(fmaxf(sqrtf(s), 1e-8f));
    } else if (tid < 128) {
        const int j = tid - 64;
        float s = 0.0f;
        #pragma unroll
        for (int k = 0; k < 16; ++k) { float v = Bt[k * 64 + j]; s = fmaf(v, v, s); }
        iB[j] = fast_rcp(fmaxf(sqrtf(s), 1e-8f));
    }
    __syncthreads();

    const int ty = tid >> 4;   // row group (4 rows)
    const int tx = tid & 15;   // col group (4 cols = 1 float4)

    float4 acc0 = {0,0,0,0}, acc1 = {0,0,0,0}, acc2 = {0,0,0,0}, acc3 = {0,0,0,0};
    #pragma unroll
    for (int kk = 0; kk < 4; ++kk) {
        float4 a0 = ((const float4*)As)[(ty * 4 + 0) * 4 + kk];
        float4 a1 = ((const float4*)As)[(ty * 4 + 1) * 4 + kk];
        float4 a2 = ((const float4*)As)[(ty * 4 + 2) * 4 + kk];
        float4 a3 = ((const float4*)As)[(ty * 4 + 3) * 4 + kk];
        #pragma unroll
        for (int e = 0; e < 4; ++e) {
            const int k = kk * 4 + e;
            float4 bk = ((const float4*)Bt)[k * 16 + tx];
            const float a0e = (e == 0) ? a0.x : (e == 1) ? a0.y : (e == 2) ? a0.z : a0.w;
            const float a1e = (e == 0) ? a1.x : (e == 1) ? a1.y : (e == 2) ? a1.z : a1.w;
            const float a2e = (e == 0) ? a2.x : (e == 1) ? a2.y : (e == 2) ? a2.z : a2.w;
            const float a3e = (e == 0) ? a3.x : (e == 1) ? a3.y : (e == 2) ? a3.z : a3.w;
            acc0.x = fmaf(a0e, bk.x, acc0.x); acc0.y = fmaf(a0e, bk.y, acc0.y);
            acc0.z = fmaf(a0e, bk.z, acc0.z); acc0.w = fmaf(a0e, bk.w, acc0.w);
            acc1.x = fmaf(a1e, bk.x, acc1.x); acc1.y = fmaf(a1e, bk.y, acc1.y);
            acc1.z = fmaf(a1e, bk.z, acc1.z); acc1.w = fmaf(a1e, bk.w, acc1.w);
            acc2.x = fmaf(a2e, bk.x, acc2.x); acc2.y = fmaf(a2e, bk.y, acc2.y);
            acc2.z = fmaf(a2e, bk.z, acc2.z); acc2.w = fmaf(a2e, bk.w, acc2.w);
            acc3.x = fmaf(a3e, bk.x, acc3.x); acc3.y = fmaf(a3e, bk.y, acc3.y);
            acc3.z = fmaf(a3e, bk.z, acc3.z); acc3.w = fmaf(a3e, bk.w, acc3.w);
        }
    }

    float* out = adj + (size_t)l * NODES * NODES;
    const float4 ib4 = ((const float4*)iB)[tx];
    #pragma unroll
    for (int ii = 0; ii < 4; ++ii) {
        const int i = i0 + ty * 4 + ii;
        const float si = iA[ty * 4 + ii];
        float4 a = (ii == 0) ? acc0 : (ii == 1) ? acc1 : (ii == 2) ? acc2 : acc3;
        float4 w;
        w.x = a.x * si * ib4.x;
        w.y = a.y * si * ib4.y;
        w.z = a.z * si * ib4.z;
        w.w = a.w * si * ib4.w;
        *(float4*)(out + (size_t)i * NODES + j0 + tx * 4) = w;
    }
}

extern "C" void kernel_launch(void* const* d_in, const int* in_sizes, int n_in,
                              void* d_out, int out_size, void* d_ws, size_t ws_size,
                              hipStream_t stream) {
    const float* inputs = (const float*)d_in[0];
    const float* w_ih   = (const float*)d_in[1];
    const float* w_hh   = (const float*)d_in[2];
    const float* b_ih   = (const float*)d_in[3];
    const float* b_hh   = (const float*)d_in[4];
    const int*   horiz  = (const int*)d_in[5];

    float* adj   = (float*)d_out;                                   // [24,1024,1024]
    float* h_out = (float*)d_out + (size_t)LAYERS * NODES * NODES;  // [1024,24,16]
    float* hv    = (float*)d_ws;                                    // [24][16384]

    // 256 blocks x 256 threads = 1024 waves; 64 chains/block (16 per wave)
    gru_pipe_kernel<<<NLANES / 64, 256, 0, stream>>>(inputs, w_ih, w_hh, b_ih, b_hh,
                                                     horiz, hv, h_out);

    dim3 grid(NODES / 64, NODES / 64, LAYERS);
    adj_kernel<<<grid, 256, 0, stream>>>(hv, adj);
}